// Round 12
// baseline (142.887 us; speedup 1.0000x reference)
//
#include <hip/hip_runtime.h>
#include <math.h>

// Problem constants
#define BB    16
#define TT    2048
#define VOCAB 14
#define TOKD  8
#define POSD  8
#define DM    16      // TOKD + POSD
#define NH    2
#define HD    3
#define AD    6       // NH*HD
#define FFND  3

#define NTOK  (BB*TT)            // 32768
#define BH    (BB*NH)            // 32
#define TPB   36                 // tiles per bh: sum_{s=0..7}(s+1)
#define NTILE (BH*TPB)           // 1152 tiles

struct P {
    const int*   idx;
    const float* tok_emb;
    const float* pos_enc;
    const float* Wq;
    const float* Wk;
    const float* Wv;
    const float* Wo;
    const float* ln1w;
    const float* ln1b;
    const float* ln2w;
    const float* ln2b;
    const float* lnfw;
    const float* lnfb;
    const float* W1;
    const float* b1;
    const float* W2;
    const float* b2;
    const float* Wh;
    float*       out;
    float4*      qbuf;   // [BH][TT] prescaled q
    float4*      kvbuf;  // [BH][TT][2] f32 records {k0,k1,k2,_},{v0,v1,v2,_}
    float4*      pbuf;   // [BH][8][TT] chunk partials {a0,a1,a2,l}, transposed
};

// ---------------------------------------------------------------------------
// Kernel 1: per-token prep (once per token).
// ---------------------------------------------------------------------------
__global__ __launch_bounds__(256) void prep_kernel(P p) {
    int gid = blockIdx.x * 256 + threadIdx.x;
    if (gid >= NTOK) return;
    int t = gid & (TT - 1);
    int b = gid >> 11;

    float x[DM];
    int tok = p.idx[gid];
    #pragma unroll
    for (int j = 0; j < TOKD; ++j) x[j]        = p.tok_emb[tok * TOKD + j];
    #pragma unroll
    for (int j = 0; j < POSD; ++j) x[TOKD + j] = p.pos_enc[t * POSD + j];

    float m = 0.f;
    #pragma unroll
    for (int j = 0; j < DM; ++j) m += x[j];
    m *= (1.f / DM);
    float v = 0.f;
    #pragma unroll
    for (int j = 0; j < DM; ++j) { float d = x[j] - m; v += d * d; }
    v *= (1.f / DM);
    float rs = rsqrtf(v + 1e-5f);
    float h[DM];
    #pragma unroll
    for (int j = 0; j < DM; ++j)
        h[j] = (x[j] - m) * rs * p.ln1w[j] + p.ln1b[j];

    float q[AD], k[AD], vv[AD];
    #pragma unroll
    for (int a = 0; a < AD; ++a) {
        float sq = 0.f, sk = 0.f, sv = 0.f;
        #pragma unroll
        for (int j = 0; j < 8; ++j) {
            sq = fmaf(p.Wq[a * 8 + j], h[TOKD + j], sq);
            sk = fmaf(p.Wk[a * 8 + j], h[TOKD + j], sk);
            sv = fmaf(p.Wv[a * 8 + j], h[j], sv);
        }
        q[a] = sq; k[a] = sk; vv[a] = sv;
    }

    const float QS = 1.4426950408889634f / 1.7320508075688772f; // log2e/sqrt(HD)
    #pragma unroll
    for (int hh = 0; hh < NH; ++hh) {
        size_t base = (size_t)(b * NH + hh) * TT + t;
        p.qbuf[base] = make_float4(q[hh*3] * QS, q[hh*3+1] * QS, q[hh*3+2] * QS, 0.f);
        p.kvbuf[base * 2]     = make_float4(k[hh*3],  k[hh*3+1],  k[hh*3+2],  0.f);
        p.kvbuf[base * 2 + 1] = make_float4(vv[hh*3], vv[hh*3+1], vv[hh*3+2], 0.f);
    }
}

// ---------------------------------------------------------------------------
// Kernel 2: attention tiles. Tile = (bh, 256-query super-row s, 256-key
// chunk c), c <= s. Wave w owns queries [64w, 64w+64) of the row (1/lane)
// and iterates ALL chunk keys via wave-uniform broadcast LDS reads (f32
// records — no cvts). No reduction, no spart: direct coalesced pbuf store.
// Diagonal tiles: wave-uniform loop split (unmasked prefix + masked 64-tail).
// ---------------------------------------------------------------------------
__global__ __launch_bounds__(256) void attn_kernel(P p) {
    __shared__ float4 skv[512];      // 8 KB: 256 records x 32B

    const int tid  = threadIdx.x;
    int tile = blockIdx.x;
    int bh   = tile / TPB;
    int r    = tile - bh * TPB;
    int s    = 0;
    while (((s + 1) * (s + 2)) / 2 <= r) ++s;
    int c    = r - (s * (s + 1)) / 2;

    // stage chunk KV (512 float4 by 256 threads) + own q (coalesced global)
    const float4* gkv = p.kvbuf + ((size_t)bh * TT + (c << 8)) * 2;
    skv[tid]       = gkv[tid];
    skv[256 + tid] = gkv[256 + tid];
    float4 qv = p.qbuf[(size_t)bh * TT + (s << 8) + tid];
    __syncthreads();

    int wv = tid >> 6;
    int lane = tid & 63;
    int kw = wv << 6;                 // diagonal split point for this wave

    float a0 = 0.f, a1 = 0.f, a2 = 0.f, l = 0.f;

    int nun = (c < s) ? 256 : kw;     // unmasked iterations
    #pragma unroll 8
    for (int it = 0; it < nun; ++it) {
        float4 kk = skv[2 * it];
        float4 vz = skv[2 * it + 1];
        float sc = fmaf(qv.x, kk.x, fmaf(qv.y, kk.y, qv.z * kk.z));
        float pr = __builtin_amdgcn_exp2f(sc);
        a0 = fmaf(pr, vz.x, a0);
        a1 = fmaf(pr, vz.y, a1);
        a2 = fmaf(pr, vz.z, a2);
        l += pr;
    }
    if (c == s) {
        // masked tail: keys [kw, kw+64), visible iff (it-kw) <= lane
        #pragma unroll 8
        for (int j = 0; j < 64; ++j) {
            float4 kk = skv[2 * (kw + j)];
            float4 vz = skv[2 * (kw + j) + 1];
            float sc = fmaf(qv.x, kk.x, fmaf(qv.y, kk.y, qv.z * kk.z));
            float pr = __builtin_amdgcn_exp2f(sc);
            pr = (j <= lane) ? pr : 0.f;
            a0 = fmaf(pr, vz.x, a0);
            a1 = fmaf(pr, vz.y, a1);
            a2 = fmaf(pr, vz.z, a2);
            l += pr;
        }
    }

    p.pbuf[((size_t)bh * 8 + c) * TT + (s << 8) + tid] =
        make_float4(a0, a1, a2, l);
}

// ---------------------------------------------------------------------------
// Kernel 3: per-token epilogue.
// ---------------------------------------------------------------------------
__global__ __launch_bounds__(256) void epi_kernel(P p) {
    int gid = blockIdx.x * 256 + threadIdx.x;
    if (gid >= NTOK) return;
    int t = gid & (TT - 1);
    int b = gid >> 11;
    int s = t >> 8;

    float x[DM];
    int tok = p.idx[gid];
    #pragma unroll
    for (int j = 0; j < TOKD; ++j) x[j]        = p.tok_emb[tok * TOKD + j];
    #pragma unroll
    for (int j = 0; j < POSD; ++j) x[TOKD + j] = p.pos_enc[t * POSD + j];

    float att[AD];
    #pragma unroll
    for (int hh = 0; hh < NH; ++hh) {
        const float4* pp = p.pbuf + ((size_t)(b * NH + hh) * 8) * TT + t;
        float4 acc = pp[0];
        for (int c = 1; c <= s; ++c) {
            float4 e = pp[(size_t)c * TT];
            acc.x += e.x; acc.y += e.y; acc.z += e.z; acc.w += e.w;
        }
        float inv = 1.f / acc.w;
        att[hh*3+0] = acc.x * inv;
        att[hh*3+1] = acc.y * inv;
        att[hh*3+2] = acc.z * inv;
    }

    float xo[DM];
    #pragma unroll
    for (int j = 0; j < DM; ++j) {
        float sacc = x[j];
        #pragma unroll
        for (int a = 0; a < AD; ++a) sacc = fmaf(p.Wo[j * AD + a], att[a], sacc);
        xo[j] = sacc;
    }

    float m = 0.f;
    #pragma unroll
    for (int j = 0; j < DM; ++j) m += xo[j];
    m *= (1.f / DM);
    float v = 0.f;
    #pragma unroll
    for (int j = 0; j < DM; ++j) { float d = xo[j] - m; v += d * d; }
    v *= (1.f / DM);
    float rs = rsqrtf(v + 1e-5f);
    float h2[DM];
    #pragma unroll
    for (int j = 0; j < DM; ++j)
        h2[j] = (xo[j] - m) * rs * p.ln2w[j] + p.ln2b[j];

    float g[FFND];
    #pragma unroll
    for (int cc = 0; cc < FFND; ++cc) {
        float f = p.b1[cc];
        #pragma unroll
        for (int j = 0; j < DM; ++j) f = fmaf(p.W1[cc * DM + j], h2[j], f);
        g[cc] = 0.5f * f * (1.f + erff(f * 0.70710678118654752f));
    }
    float x2[DM];
    #pragma unroll
    for (int j = 0; j < DM; ++j) {
        float sacc = xo[j] + p.b2[j];
        #pragma unroll
        for (int cc = 0; cc < FFND; ++cc) sacc = fmaf(p.W2[j * FFND + cc], g[cc], sacc);
        x2[j] = sacc;
    }

    m = 0.f;
    #pragma unroll
    for (int j = 0; j < DM; ++j) m += x2[j];
    m *= (1.f / DM);
    v = 0.f;
    #pragma unroll
    for (int j = 0; j < DM; ++j) { float d = x2[j] - m; v += d * d; }
    v *= (1.f / DM);
    rs = rsqrtf(v + 1e-5f);
    float y[DM];
    #pragma unroll
    for (int j = 0; j < DM; ++j)
        y[j] = (x2[j] - m) * rs * p.lnfw[j] + p.lnfb[j];

    float t8[TOKD];
    #pragma unroll
    for (int pp = 0; pp < TOKD; ++pp) {
        float sacc = 0.f;
        #pragma unroll
        for (int j = 0; j < DM; ++j) sacc = fmaf(p.Wh[pp * DM + j], y[j], sacc);
        t8[pp] = sacc;
    }
    float* op = p.out + (size_t)gid * VOCAB;
    #pragma unroll
    for (int vcb = 0; vcb < VOCAB; ++vcb) {
        float sacc = 0.f;
        #pragma unroll
        for (int pp = 0; pp < TOKD; ++pp)
            sacc = fmaf(t8[pp], p.tok_emb[vcb * TOKD + pp], sacc);
        op[vcb] = sacc;
    }
}

// ---------------------------------------------------------------------------
extern "C" void kernel_launch(void* const* d_in, const int* in_sizes, int n_in,
                              void* d_out, int out_size, void* d_ws, size_t ws_size,
                              hipStream_t stream) {
    P p;
    p.idx     = (const int*)d_in[0];
    p.tok_emb = (const float*)d_in[1];
    p.pos_enc = (const float*)d_in[2];
    p.Wq      = (const float*)d_in[3];
    p.Wk      = (const float*)d_in[4];
    p.Wv      = (const float*)d_in[5];
    p.Wo      = (const float*)d_in[6];
    p.ln1w    = (const float*)d_in[7];
    p.ln1b    = (const float*)d_in[8];
    p.ln2w    = (const float*)d_in[9];
    p.ln2b    = (const float*)d_in[10];
    p.lnfw    = (const float*)d_in[11];
    p.lnfb    = (const float*)d_in[12];
    p.W1      = (const float*)d_in[13];
    p.b1      = (const float*)d_in[14];
    p.W2      = (const float*)d_in[15];
    p.b2      = (const float*)d_in[16];
    p.Wh      = (const float*)d_in[17];
    p.out     = (float*)d_out;
    p.qbuf    = (float4*)d_ws;                                  // 1 MB
    p.kvbuf   = (float4*)((char*)d_ws + (1u << 20));            // 2 MB
    p.pbuf    = (float4*)((char*)d_ws + (3u << 20));            // 8 MB

    prep_kernel<<<NTOK / 256, 256, 0, stream>>>(p);
    attn_kernel<<<NTILE, 256, 0, stream>>>(p);
    epi_kernel<<<NTOK / 256, 256, 0, stream>>>(p);
}

// Round 13
// 131.932 us; speedup vs baseline: 1.0830x; 1.0830x over previous
//
#include <hip/hip_runtime.h>
#include <hip/hip_fp16.h>
#include <math.h>

// Problem constants
#define BB    16
#define TT    2048
#define VOCAB 14
#define TOKD  8
#define POSD  8
#define DM    16      // TOKD + POSD
#define NH    2
#define HD    3
#define AD    6       // NH*HD
#define FFND  3

#define NTOK  (BB*TT)            // 32768
#define BH    (BB*NH)            // 32
#define TPB   36                 // tiles per bh: sum_{s=0..7}(s+1)
#define NTILE (BH*TPB)           // 1152 tiles

typedef _Float16 h2_t __attribute__((ext_vector_type(2)));

__device__ __forceinline__ h2_t as_h2(unsigned int u) {
    union { unsigned int u; h2_t h; } c; c.u = u; return c.h;
}

// score = q·k from packed f16 halves, f32 result
__device__ __forceinline__ float dot3_h(unsigned q01, unsigned q2x,
                                        unsigned k01, unsigned k2x) {
#if defined(__has_builtin)
#if __has_builtin(__builtin_amdgcn_fdot2)
    return __builtin_amdgcn_fdot2(as_h2(q01), as_h2(k01),
           __builtin_amdgcn_fdot2(as_h2(q2x), as_h2(k2x), 0.f, false), false);
#else
    goto fallback;
#endif
#endif
fallback:
    {
        float2 qa = __half22float2(*(const __half2*)&q01);
        float2 qb = __half22float2(*(const __half2*)&q2x);
        float2 ka = __half22float2(*(const __half2*)&k01);
        float2 kb = __half22float2(*(const __half2*)&k2x);
        return fmaf(qa.x, ka.x, fmaf(qa.y, ka.y, qb.x * kb.x));
    }
}

struct P {
    const int*   idx;
    const float* tok_emb;
    const float* pos_enc;
    const float* Wq;
    const float* Wk;
    const float* Wv;
    const float* Wo;
    const float* ln1w;
    const float* ln1b;
    const float* ln2w;
    const float* ln2b;
    const float* lnfw;
    const float* lnfb;
    const float* W1;
    const float* b1;
    const float* W2;
    const float* b2;
    const float* Wh;
    float*       out;
    uint2*       qpk;    // [BH][TT] packed f16 q: {q0,q1},{q2,0} (prescaled)
    uint4*       kvh;    // [BH][TT] packed f16 kv: {k0,k1},{k2,0},{v0,v1},{v2,0}
    float4*      pbuf;   // [BH][8][TT] chunk partials {a0,a1,a2,l}, transposed
};

// ---------------------------------------------------------------------------
// Kernel 1: per-token prep (once per token).
// ---------------------------------------------------------------------------
__global__ __launch_bounds__(256) void prep_kernel(P p) {
    int gid = blockIdx.x * 256 + threadIdx.x;
    if (gid >= NTOK) return;
    int t = gid & (TT - 1);
    int b = gid >> 11;

    float x[DM];
    int tok = p.idx[gid];
    #pragma unroll
    for (int j = 0; j < TOKD; ++j) x[j]        = p.tok_emb[tok * TOKD + j];
    #pragma unroll
    for (int j = 0; j < POSD; ++j) x[TOKD + j] = p.pos_enc[t * POSD + j];

    float m = 0.f;
    #pragma unroll
    for (int j = 0; j < DM; ++j) m += x[j];
    m *= (1.f / DM);
    float v = 0.f;
    #pragma unroll
    for (int j = 0; j < DM; ++j) { float d = x[j] - m; v += d * d; }
    v *= (1.f / DM);
    float rs = rsqrtf(v + 1e-5f);
    float h[DM];
    #pragma unroll
    for (int j = 0; j < DM; ++j)
        h[j] = (x[j] - m) * rs * p.ln1w[j] + p.ln1b[j];

    float q[AD], k[AD], vv[AD];
    #pragma unroll
    for (int a = 0; a < AD; ++a) {
        float sq = 0.f, sk = 0.f, sv = 0.f;
        #pragma unroll
        for (int j = 0; j < 8; ++j) {
            sq = fmaf(p.Wq[a * 8 + j], h[TOKD + j], sq);
            sk = fmaf(p.Wk[a * 8 + j], h[TOKD + j], sk);
            sv = fmaf(p.Wv[a * 8 + j], h[j], sv);
        }
        q[a] = sq; k[a] = sk; vv[a] = sv;
    }

    const float QS = 1.4426950408889634f / 1.7320508075688772f; // log2e/sqrt(HD)
    #pragma unroll
    for (int hh = 0; hh < NH; ++hh) {
        size_t base = (size_t)(b * NH + hh) * TT + t;
        __half2 qa = __floats2half2_rn(q[hh*3] * QS, q[hh*3+1] * QS);
        __half2 qb = __floats2half2_rn(q[hh*3+2] * QS, 0.f);
        uint2 qp;
        qp.x = *reinterpret_cast<unsigned int*>(&qa);
        qp.y = *reinterpret_cast<unsigned int*>(&qb);
        p.qpk[base] = qp;

        __half2 ka = __floats2half2_rn(k[hh*3],   k[hh*3+1]);
        __half2 kb = __floats2half2_rn(k[hh*3+2], 0.f);
        __half2 va = __floats2half2_rn(vv[hh*3],  vv[hh*3+1]);
        __half2 vb = __floats2half2_rn(vv[hh*3+2], 0.f);
        uint4 rec;
        rec.x = *reinterpret_cast<unsigned int*>(&ka);
        rec.y = *reinterpret_cast<unsigned int*>(&kb);
        rec.z = *reinterpret_cast<unsigned int*>(&va);
        rec.w = *reinterpret_cast<unsigned int*>(&vb);
        p.kvh[base] = rec;
    }
}

// ---------------------------------------------------------------------------
// Kernel 2: attention tiles (R11 geometry — the measured-best layout).
// Tile = (bh, 256-query super-row s, 256-key chunk c), c <= s. Wave wv
// covers keys [64wv, 64wv+64); lane owns queries 64j+lane, j=0..3. One
// broadcast ds_read_b128 per key serves 256 query*key pairs. Scores via
// v_dot2_f32_f16 (packed f16 q,k). Diagonal tiles: wave-uniform group split.
// Block LDS reduce; coalesced transposed pbuf store.
// ---------------------------------------------------------------------------
__global__ __launch_bounds__(256) void attn_kernel(P p) {
    __shared__ uint4  skv[256];      // 4 KB
    __shared__ uint2  sq[256];       // 2 KB
    __shared__ float4 spart[1024];   // 16 KB

    const int tid  = threadIdx.x;
    int tile = blockIdx.x;
    int bh   = tile / TPB;
    int r    = tile - bh * TPB;
    int s    = 0;
    while (((s + 1) * (s + 2)) / 2 <= r) ++s;
    int c    = r - (s * (s + 1)) / 2;

    skv[tid] = p.kvh[(size_t)bh * TT + (c << 8) + tid];
    sq [tid] = p.qpk[(size_t)bh * TT + (s << 8) + tid];
    __syncthreads();

    int wv   = tid >> 6;
    int lane = tid & 63;
    int kw   = wv << 6;

    uint2 qr[4];
    #pragma unroll
    for (int j = 0; j < 4; ++j) qr[j] = sq[(j << 6) + lane];

    float ac[4][4];
    #pragma unroll
    for (int j = 0; j < 4; ++j)
        ac[j][0] = ac[j][1] = ac[j][2] = ac[j][3] = 0.f;

    if (c < s) {
        #pragma unroll 4
        for (int it = 0; it < 64; ++it) {
            uint4 rec = skv[kw + it];
            float2 vab = __half22float2(*reinterpret_cast<const __half2*>(&rec.z));
            float  v2  = __half22float2(*reinterpret_cast<const __half2*>(&rec.w)).x;
            #pragma unroll
            for (int j = 0; j < 4; ++j) {
                float sc = dot3_h(qr[j].x, qr[j].y, rec.x, rec.y);
                float pr = __builtin_amdgcn_exp2f(sc);
                ac[j][0] = fmaf(pr, vab.x, ac[j][0]);
                ac[j][1] = fmaf(pr, vab.y, ac[j][1]);
                ac[j][2] = fmaf(pr, v2,    ac[j][2]);
                ac[j][3] += pr;
            }
        }
    } else {
        // diagonal tile: group j<wv fully masked (skip); j==wv triangular;
        // j>wv unmasked — all wave-uniform branches.
        #pragma unroll
        for (int j = 0; j < 4; ++j) {
            if (j < wv) continue;
            if (j == wv) {
                #pragma unroll 4
                for (int it = 0; it < 64; ++it) {
                    uint4 rec = skv[kw + it];
                    float2 vab = __half22float2(*reinterpret_cast<const __half2*>(&rec.z));
                    float  v2  = __half22float2(*reinterpret_cast<const __half2*>(&rec.w)).x;
                    float sc = dot3_h(qr[j].x, qr[j].y, rec.x, rec.y);
                    float pr = __builtin_amdgcn_exp2f(sc);
                    pr = (it <= lane) ? pr : 0.f;
                    ac[j][0] = fmaf(pr, vab.x, ac[j][0]);
                    ac[j][1] = fmaf(pr, vab.y, ac[j][1]);
                    ac[j][2] = fmaf(pr, v2,    ac[j][2]);
                    ac[j][3] += pr;
                }
            } else {
                #pragma unroll 4
                for (int it = 0; it < 64; ++it) {
                    uint4 rec = skv[kw + it];
                    float2 vab = __half22float2(*reinterpret_cast<const __half2*>(&rec.z));
                    float  v2  = __half22float2(*reinterpret_cast<const __half2*>(&rec.w)).x;
                    float sc = dot3_h(qr[j].x, qr[j].y, rec.x, rec.y);
                    float pr = __builtin_amdgcn_exp2f(sc);
                    ac[j][0] = fmaf(pr, vab.x, ac[j][0]);
                    ac[j][1] = fmaf(pr, vab.y, ac[j][1]);
                    ac[j][2] = fmaf(pr, v2,    ac[j][2]);
                    ac[j][3] += pr;
                }
            }
        }
    }

    // per-wave partials (16B lane stride: 2-way, free)
    #pragma unroll
    for (int j = 0; j < 4; ++j)
        spart[(wv << 8) + (j << 6) + lane] =
            make_float4(ac[j][0], ac[j][1], ac[j][2], ac[j][3]);
    __syncthreads();

    // block reduce across 4 waves; coalesced transposed pbuf store
    float4 p0 = spart[tid];
    float4 p1 = spart[256 + tid];
    float4 p2 = spart[512 + tid];
    float4 p3 = spart[768 + tid];
    float4 acc = make_float4(p0.x+p1.x+p2.x+p3.x, p0.y+p1.y+p2.y+p3.y,
                             p0.z+p1.z+p2.z+p3.z, p0.w+p1.w+p2.w+p3.w);
    p.pbuf[((size_t)bh * 8 + c) * TT + (s << 8) + tid] = acc;
}

// ---------------------------------------------------------------------------
// Kernel 3: per-token epilogue.
// ---------------------------------------------------------------------------
__global__ __launch_bounds__(256) void epi_kernel(P p) {
    int gid = blockIdx.x * 256 + threadIdx.x;
    if (gid >= NTOK) return;
    int t = gid & (TT - 1);
    int b = gid >> 11;
    int s = t >> 8;

    float x[DM];
    int tok = p.idx[gid];
    #pragma unroll
    for (int j = 0; j < TOKD; ++j) x[j]        = p.tok_emb[tok * TOKD + j];
    #pragma unroll
    for (int j = 0; j < POSD; ++j) x[TOKD + j] = p.pos_enc[t * POSD + j];

    float att[AD];
    #pragma unroll
    for (int hh = 0; hh < NH; ++hh) {
        const float4* pp = p.pbuf + ((size_t)(b * NH + hh) * 8) * TT + t;
        float4 acc = pp[0];
        for (int c = 1; c <= s; ++c) {
            float4 e = pp[(size_t)c * TT];
            acc.x += e.x; acc.y += e.y; acc.z += e.z; acc.w += e.w;
        }
        float inv = 1.f / acc.w;
        att[hh*3+0] = acc.x * inv;
        att[hh*3+1] = acc.y * inv;
        att[hh*3+2] = acc.z * inv;
    }

    float xo[DM];
    #pragma unroll
    for (int j = 0; j < DM; ++j) {
        float sacc = x[j];
        #pragma unroll
        for (int a = 0; a < AD; ++a) sacc = fmaf(p.Wo[j * AD + a], att[a], sacc);
        xo[j] = sacc;
    }

    float m = 0.f;
    #pragma unroll
    for (int j = 0; j < DM; ++j) m += xo[j];
    m *= (1.f / DM);
    float v = 0.f;
    #pragma unroll
    for (int j = 0; j < DM; ++j) { float d = xo[j] - m; v += d * d; }
    v *= (1.f / DM);
    float rs = rsqrtf(v + 1e-5f);
    float h2[DM];
    #pragma unroll
    for (int j = 0; j < DM; ++j)
        h2[j] = (xo[j] - m) * rs * p.ln2w[j] + p.ln2b[j];

    float g[FFND];
    #pragma unroll
    for (int cc = 0; cc < FFND; ++cc) {
        float f = p.b1[cc];
        #pragma unroll
        for (int j = 0; j < DM; ++j) f = fmaf(p.W1[cc * DM + j], h2[j], f);
        g[cc] = 0.5f * f * (1.f + erff(f * 0.70710678118654752f));
    }
    float x2[DM];
    #pragma unroll
    for (int j = 0; j < DM; ++j) {
        float sacc = xo[j] + p.b2[j];
        #pragma unroll
        for (int cc = 0; cc < FFND; ++cc) sacc = fmaf(p.W2[j * FFND + cc], g[cc], sacc);
        x2[j] = sacc;
    }

    m = 0.f;
    #pragma unroll
    for (int j = 0; j < DM; ++j) m += x2[j];
    m *= (1.f / DM);
    v = 0.f;
    #pragma unroll
    for (int j = 0; j < DM; ++j) { float d = x2[j] - m; v += d * d; }
    v *= (1.f / DM);
    rs = rsqrtf(v + 1e-5f);
    float y[DM];
    #pragma unroll
    for (int j = 0; j < DM; ++j)
        y[j] = (x2[j] - m) * rs * p.lnfw[j] + p.lnfb[j];

    float t8[TOKD];
    #pragma unroll
    for (int pp = 0; pp < TOKD; ++pp) {
        float sacc = 0.f;
        #pragma unroll
        for (int j = 0; j < DM; ++j) sacc = fmaf(p.Wh[pp * DM + j], y[j], sacc);
        t8[pp] = sacc;
    }
    float* op = p.out + (size_t)gid * VOCAB;
    #pragma unroll
    for (int vcb = 0; vcb < VOCAB; ++vcb) {
        float sacc = 0.f;
        #pragma unroll
        for (int pp = 0; pp < TOKD; ++pp)
            sacc = fmaf(t8[pp], p.tok_emb[vcb * TOKD + pp], sacc);
        op[vcb] = sacc;
    }
}

// ---------------------------------------------------------------------------
extern "C" void kernel_launch(void* const* d_in, const int* in_sizes, int n_in,
                              void* d_out, int out_size, void* d_ws, size_t ws_size,
                              hipStream_t stream) {
    P p;
    p.idx     = (const int*)d_in[0];
    p.tok_emb = (const float*)d_in[1];
    p.pos_enc = (const float*)d_in[2];
    p.Wq      = (const float*)d_in[3];
    p.Wk      = (const float*)d_in[4];
    p.Wv      = (const float*)d_in[5];
    p.Wo      = (const float*)d_in[6];
    p.ln1w    = (const float*)d_in[7];
    p.ln1b    = (const float*)d_in[8];
    p.ln2w    = (const float*)d_in[9];
    p.ln2b    = (const float*)d_in[10];
    p.lnfw    = (const float*)d_in[11];
    p.lnfb    = (const float*)d_in[12];
    p.W1      = (const float*)d_in[13];
    p.b1      = (const float*)d_in[14];
    p.W2      = (const float*)d_in[15];
    p.b2      = (const float*)d_in[16];
    p.Wh      = (const float*)d_in[17];
    p.out     = (float*)d_out;
    p.qpk     = (uint2*)d_ws;                                   // 0.5 MB
    p.kvh     = (uint4*)((char*)d_ws + (1u << 20));             // 1 MB
    p.pbuf    = (float4*)((char*)d_ws + (2u << 20));            // 8 MB

    prep_kernel<<<NTOK / 256, 256, 0, stream>>>(p);
    attn_kernel<<<NTILE, 256, 0, stream>>>(p);
    epi_kernel<<<NTOK / 256, 256, 0, stream>>>(p);
}